// Round 5
// baseline (516.150 us; speedup 1.0000x reference)
//
#include <hip/hip_runtime.h>

#define NVOX 400000
#define K27 27
#define EPS_ 1e-5f

typedef short short8 __attribute__((ext_vector_type(8)));
typedef float floatx4 __attribute__((ext_vector_type(4)));
typedef float floatx16 __attribute__((ext_vector_type(16)));
typedef unsigned int uintx4 __attribute__((ext_vector_type(4)));

// round-to-nearest-even fp32 -> bf16, packed pair (a low 16, b high 16)
__device__ __forceinline__ unsigned int pack2bf(float a, float b) {
    unsigned int ua = __builtin_bit_cast(unsigned int, a);
    unsigned int ub = __builtin_bit_cast(unsigned int, b);
    ua += 0x7fffu + ((ua >> 16) & 1u);
    ub += 0x7fffu + ((ub >> 16) & 1u);
    return (ua >> 16) | (ub & 0xffff0000u);
}

// blocks [0, fb): fp32->bf16 feature conversion (8 elems/thread)
// blocks [fb, fb+32): W[k][ci][co] -> wt[k][co][ci] bf16 (32 blocks: no serial tail)
// block  fb+32: zero the 128 stats accumulators
__global__ void prep_kernel(const float* __restrict__ w,
                            const float* __restrict__ feat,
                            unsigned short* __restrict__ feat_bf,
                            unsigned short* __restrict__ wt,
                            float* __restrict__ sums,
                            int fb) {
    const int b = blockIdx.x;
    const int t = threadIdx.x;
    if (b < fb) {
        const int i0 = b * 2048 + t * 8;
        const floatx4* s = (const floatx4*)(feat + i0);
        const floatx4 f0 = s[0], f1 = s[1];
        uintx4 v;
        v[0] = pack2bf(f0[0], f0[1]); v[1] = pack2bf(f0[2], f0[3]);
        v[2] = pack2bf(f1[0], f1[1]); v[3] = pack2bf(f1[2], f1[3]);
        *(uintx4*)(feat_bf + i0) = v;
    } else if (b < fb + 32) {
        for (int g = (b - fb) * 256 + t; g < K27 * 64 * 64; g += 32 * 256) {
            const int k = g >> 12, r = g & 4095, co = r >> 6, ci = r & 63;
            unsigned int u =
                __builtin_bit_cast(unsigned int, w[(k << 12) + (ci << 6) + co]);
            u += 0x7fffu + ((u >> 16) & 1u);
            wt[g] = (unsigned short)(u >> 16);
        }
    } else {
        if (t < 128) sums[t] = 0.0f;
    }
}

// 256 rows x 64 out-ch per block; 4 waves, wave tile M=64 x N=64 via 2x2
// mfma_f32_32x32x16_bf16 (acc 2x2x16). Activity mask (1 bit per (row,k))
// lets us SKIP ds_writes for the ~81% inactive rows and mask af fragments
// at read time (stale LDS -> 0). Gathers keep 8 consecutive lanes per row
// (cheap TA). Register prefetch pipelines gather k+1 under MFMA k.
// LDS 16B chunks XOR-swizzled by row&7 (row stride 128B would 32-way alias).
template <bool BF16FEAT>
__launch_bounds__(256)
__global__ void conv_mfma(const float* __restrict__ feat,
                          const unsigned short* __restrict__ feat_bf,
                          const int* __restrict__ nmap,
                          const unsigned short* __restrict__ wt,
                          float* __restrict__ out,
                          float* __restrict__ sums,
                          int nchunks) {
    __shared__ __align__(16) unsigned short a_tile[256 * 64];  // 32 KB
    __shared__ __align__(16) unsigned short b_tile[64 * 64];   //  8 KB
    __shared__ unsigned amask[256];
    __shared__ float cstat[128];

    // XCD-contiguous chunk swizzle (8 XCDs round-robin assumed; speed-only)
    const int bpx = (nchunks + 7) / 8;
    const int chunk = (blockIdx.x & 7) * bpx + (blockIdx.x >> 3);
    if (chunk >= nchunks) return;
    const int base = chunk * 256;

    const int tid  = threadIdx.x;
    const int wv   = tid >> 6;
    const int lane = tid & 63;
    const int l31  = lane & 31;
    const int h    = lane >> 5;

    // ---- activity mask: thread t covers row base+t
    unsigned am = 0;
    if (base + tid < NVOX) {
#pragma unroll
        for (int k = 0; k < K27; ++k)
            am |= ((unsigned)(nmap[k * NVOX + base + tid] >= 0)) << k;
    }
    amask[tid] = am;
    if (tid < 128) cstat[tid] = 0.0f;
    __syncthreads();

    // ---- gather/staging descriptors: lane covers rows wv*64+i*8+(lane>>3),
    // chunk gc = lane&7 (8 consecutive lanes per row -> coalesced gather)
    const int gr = lane >> 3, gc = lane & 7;
    int grows[8], apos[8];
    unsigned gm[8];
#pragma unroll
    for (int i = 0; i < 8; ++i) {
        grows[i] = wv * 64 + i * 8 + gr;
        apos[i]  = (grows[i] * 8 + (gc ^ (grows[i] & 7))) * 8;
        gm[i]    = amask[grows[i]];
    }
    int bpos[2], bsrc[2];
#pragma unroll
    for (int j = 0; j < 2; ++j) {
        const int c = tid + 256 * j;
        bsrc[j] = c * 8;
        bpos[j] = ((c >> 3) * 8 + ((c & 7) ^ ((c >> 3) & 7))) * 8;
    }
    // af read rows + their masks (k-invariant)
    int row_a[2];
    unsigned am_a[2];
#pragma unroll
    for (int mt = 0; mt < 2; ++mt) {
        row_a[mt] = wv * 64 + mt * 32 + l31;
        am_a[mt]  = amask[row_a[mt]];
    }

    floatx16 acc[2][2];
#pragma unroll
    for (int mt = 0; mt < 2; ++mt)
#pragma unroll
        for (int nt = 0; nt < 2; ++nt)
#pragma unroll
            for (int r = 0; r < 16; ++r) acc[mt][nt][r] = 0.0f;

    short8 areg[8], breg[2];

#define PREFETCH(kk)                                                          \
    do {                                                                      \
        _Pragma("unroll") for (int i = 0; i < 8; ++i) {                       \
            if ((gm[i] >> (kk)) & 1u) {                                       \
                const int idx = nmap[(kk) * NVOX + base + grows[i]];          \
                if (BF16FEAT) {                                               \
                    areg[i] = *(const short8*)(feat_bf +                      \
                                               (size_t)idx * 64 + gc * 8);    \
                } else {                                                      \
                    const floatx4* s =                                        \
                        (const floatx4*)(feat + (size_t)idx * 64 + gc * 8);   \
                    const floatx4 f0 = s[0], f1 = s[1];                       \
                    uintx4 v;                                                 \
                    v[0] = pack2bf(f0[0], f0[1]);                             \
                    v[1] = pack2bf(f0[2], f0[3]);                             \
                    v[2] = pack2bf(f1[0], f1[1]);                             \
                    v[3] = pack2bf(f1[2], f1[3]);                             \
                    areg[i] = __builtin_bit_cast(short8, v);                  \
                }                                                             \
            }                                                                 \
        }                                                                     \
        _Pragma("unroll") for (int j = 0; j < 2; ++j) {                       \
            breg[j] = *(const short8*)(wt + (kk) * 4096 + bsrc[j]);           \
        }                                                                     \
    } while (0)

    PREFETCH(0);

    for (int k = 0; k < K27; ++k) {
        __syncthreads();  // all waves done reading iter k-1's tiles
#pragma unroll
        for (int i = 0; i < 8; ++i)
            if ((gm[i] >> k) & 1u) *(short8*)(a_tile + apos[i]) = areg[i];
#pragma unroll
        for (int j = 0; j < 2; ++j) *(short8*)(b_tile + bpos[j]) = breg[j];
        __syncthreads();  // writes visible

        if (k + 1 < K27) PREFETCH(k + 1);  // overlaps the MFMAs below

#pragma unroll
        for (int kb = 0; kb < 4; ++kb) {
            short8 af[2], bf2[2];
#pragma unroll
            for (int mt = 0; mt < 2; ++mt) {
                af[mt] = *(const short8*)(
                    a_tile + (row_a[mt] * 8 +
                              ((kb * 2 + h) ^ (row_a[mt] & 7))) * 8);
                if (!((am_a[mt] >> k) & 1u))
                    af[mt] = (short8){0, 0, 0, 0, 0, 0, 0, 0};
            }
#pragma unroll
            for (int nt = 0; nt < 2; ++nt) {
                const int rb = nt * 32 + l31;
                bf2[nt] = *(const short8*)(
                    b_tile + (rb * 8 + ((kb * 2 + h) ^ (rb & 7))) * 8);
            }
#pragma unroll
            for (int mt = 0; mt < 2; ++mt)
#pragma unroll
                for (int nt = 0; nt < 2; ++nt)
                    acc[mt][nt] = __builtin_amdgcn_mfma_f32_32x32x16_bf16(
                        af[mt], bf2[nt], acc[mt][nt], 0, 0, 0);
        }
    }
#undef PREFETCH

    // epilogue. 32x32 C/D layout (m74/m101): col=lane&31,
    // row = (reg&3) + 8*(reg>>2) + 4*(lane>>5)
#pragma unroll
    for (int mt = 0; mt < 2; ++mt)
#pragma unroll
        for (int nt = 0; nt < 2; ++nt) {
            const int col = nt * 32 + l31;
#pragma unroll
            for (int r = 0; r < 16; ++r) {
                const int dr   = (r & 3) + 8 * (r >> 2) + 4 * h;
                const int orow = base + wv * 64 + mt * 32 + dr;
                if (orow < NVOX)
                    out[(size_t)orow * 64 + col] = acc[mt][nt][r];
            }
        }
    // stats: inactive/garbage rows have acc==0 (masked) -> contribute 0
#pragma unroll
    for (int nt = 0; nt < 2; ++nt) {
        float s = 0.0f, s2 = 0.0f;
#pragma unroll
        for (int mt = 0; mt < 2; ++mt)
#pragma unroll
            for (int r = 0; r < 16; ++r) {
                const float v = acc[mt][nt][r];
                s += v;
                s2 += v * v;
            }
        s  += __shfl_xor(s, 32, 64);
        s2 += __shfl_xor(s2, 32, 64);
        if (h == 0) {
            atomicAdd(&cstat[nt * 32 + l31], s);
            atomicAdd(&cstat[64 + nt * 32 + l31], s2);
        }
    }
    __syncthreads();
    if (tid < 128) atomicAdd(&sums[tid], cstat[tid]);
}

__global__ void bn_apply(float* __restrict__ out, const float* __restrict__ sums,
                         const float* __restrict__ gamma,
                         const float* __restrict__ beta) {
    __shared__ float sc[64];
    __shared__ float sh[64];
    const int tid = threadIdx.x;
    if (tid < 64) {
        const float inv_n = 1.0f / (float)NVOX;
        const float mean = sums[tid] * inv_n;
        const float var  = sums[64 + tid] * inv_n - mean * mean;
        const float g    = gamma[tid] * rsqrtf(var + EPS_);
        sc[tid] = g;
        sh[tid] = beta[tid] - mean * g;
    }
    __syncthreads();
    const int cg = (tid & 15) * 4;
    floatx4 scale, shift;
#pragma unroll
    for (int j = 0; j < 4; ++j) {
        scale[j] = sc[cg + j];
        shift[j] = sh[cg + j];
    }
    floatx4* p = (floatx4*)out;
    const int total4 = NVOX * 16;
    for (int i = blockIdx.x * 256 + tid; i < total4; i += gridDim.x * 256) {
        floatx4 v = p[i] * scale + shift;
#pragma unroll
        for (int j = 0; j < 4; ++j) v[j] = v[j] > 0.f ? v[j] : 0.f;
        p[i] = v;
    }
}

extern "C" void kernel_launch(void* const* d_in, const int* in_sizes, int n_in,
                              void* d_out, int out_size, void* d_ws, size_t ws_size,
                              hipStream_t stream) {
    const float* feat  = (const float*)d_in[0];
    const int*   nmap  = (const int*)d_in[1];
    const float* w     = (const float*)d_in[2];
    const float* gamma = (const float*)d_in[3];
    const float* beta  = (const float*)d_in[4];
    float* out = (float*)d_out;

    const size_t FEATB = (size_t)NVOX * 64 * 2;      // 51,200,000
    const size_t WTB   = (size_t)K27 * 64 * 64 * 2;  //    221,184
    const int nchunks  = (NVOX + 255) / 256;         // 1563
    const int grid     = ((nchunks + 7) / 8) * 8;    // 1568 (5 early-exit)

    if (ws_size >= FEATB + WTB + 512) {
        unsigned short* feat_bf = (unsigned short*)d_ws;
        unsigned short* wt      = (unsigned short*)((char*)d_ws + FEATB);
        float* sums             = (float*)((char*)d_ws + FEATB + WTB);
        prep_kernel<<<dim3(12533), dim3(256), 0, stream>>>(
            w, feat, feat_bf, wt, sums, 12500);
        conv_mfma<true><<<dim3(grid), dim3(256), 0, stream>>>(
            feat, feat_bf, nmap, wt, out, sums, nchunks);
        bn_apply<<<dim3(2048), dim3(256), 0, stream>>>(out, sums, gamma, beta);
    } else {
        // fallback: fp32 gather + in-register pack (no feature buffer)
        unsigned short* wt = (unsigned short*)d_ws;
        float* sums        = (float*)((char*)d_ws + WTB);
        prep_kernel<<<dim3(33), dim3(256), 0, stream>>>(
            w, feat, nullptr, wt, sums, 0);
        conv_mfma<false><<<dim3(grid), dim3(256), 0, stream>>>(
            feat, nullptr, nmap, wt, out, sums, nchunks);
        bn_apply<<<dim3(2048), dim3(256), 0, stream>>>(out, sums, gamma, beta);
    }
}